// Round 1
// baseline (389.793 us; speedup 1.0000x reference)
//
#include <hip/hip_runtime.h>
#include <math.h>
#include <stdint.h>

#define H 2048
#define HH (H * H)
#define NB 256

// ws layout:
//   [0]      double accum                      (8 B)
//   [64]     uint32 hist[6][256]               (6144 B)  dst c0..2, then ref c0..2
//   [8192]   float  table[3][256]              (3072 B)
//   [16384]  uint32 bits[HH/32]                (524288 B) scatter membership bitmask

__global__ void k_init(uint32_t* __restrict__ hist, double* __restrict__ accum,
                       uint32_t* __restrict__ bits) {
    int tid = blockIdx.x * blockDim.x + threadIdx.x;
    if (tid == 0) *accum = 0.0;
    if (tid < 6 * NB) hist[tid] = 0u;
    int nw = HH / 32;  // 131072 words
    for (int i = tid; i < nw; i += gridDim.x * blockDim.x) bits[i] = 0u;
}

__device__ __forceinline__ float de_norm255(float x) {
    return fminf(fmaxf((x + 1.0f) * 0.5f, 0.0f), 1.0f) * 255.0f;
}

__global__ void k_hist(const float* __restrict__ tgt, const float* __restrict__ ref,
                       const float* __restrict__ msrc, const float* __restrict__ mtar,
                       const int* __restrict__ i0, const int* __restrict__ i1,
                       const int* __restrict__ i2, const int* __restrict__ i3,
                       uint32_t* __restrict__ hist, uint32_t* __restrict__ bits,
                       int nidx) {
    __shared__ uint32_t lh[6 * NB];
    for (int i = threadIdx.x; i < 6 * NB; i += blockDim.x) lh[i] = 0u;
    __syncthreads();
    int stride = gridDim.x * blockDim.x;
    for (int k = blockIdx.x * blockDim.x + threadIdx.x; k < nidx; k += stride) {
        int pa = i0[k] * H + i1[k];   // dst (ref_masked) gather position
        int pb = i2[k] * H + i3[k];   // ref (target_masked) gather position
        float ms = msrc[pa];
        float mt = mtar[pb];
        atomicOr(&bits[pa >> 5], 1u << (pa & 31));
#pragma unroll
        for (int c = 0; c < 3; ++c) {
            float vd = de_norm255(ref[c * HH + pa]) * ms;
            int bd = (int)floorf(vd);
            bd = min(max(bd, 0), NB - 1);
            atomicAdd(&lh[c * NB + bd], 1u);
            float vr = de_norm255(tgt[c * HH + pb]) * mt;
            int br = (int)floorf(vr);
            br = min(max(br, 0), NB - 1);
            atomicAdd(&lh[(3 + c) * NB + br], 1u);
        }
    }
    __syncthreads();
    for (int i = threadIdx.x; i < 6 * NB; i += blockDim.x)
        if (lh[i]) atomicAdd(&hist[i], lh[i]);
}

// 3 blocks (one per channel) x 256 threads
__global__ void k_table(const uint32_t* __restrict__ hist, float* __restrict__ table) {
    int c = blockIdx.x;
    int t = threadIdx.x;
    __shared__ uint32_t cd[NB], cr[NB];
    __shared__ float r[NB], a[NB];
    cd[t] = hist[c * NB + t];
    cr[t] = hist[(3 + c) * NB + t];
    __syncthreads();
    if (t == 0) {
        uint32_t s = 0;
        for (int i = 0; i < NB; ++i) { s += cd[i]; cd[i] = s; }
        s = 0;
        for (int i = 0; i < NB; ++i) { s += cr[i]; cr[i] = s; }
    }
    __syncthreads();
    float totd = (float)cd[NB - 1];
    float totr = (float)cr[NB - 1];
    r[t] = (float)cd[t] / totd;   // cdf_dst
    a[t] = (float)cr[t] / totr;   // cdf_ref
    __syncthreads();
    float out;
    if (t == 0) {
        out = 0.0f;
    } else if (t == NB - 1) {
        out = (float)(NB - 1);
    } else {
        float ri = r[t];
        int j = -1;
        for (int jj = 0; jj < NB - 1; ++jj) {
            if (ri >= a[jj] && ri <= a[jj + 1]) { j = jj; break; }
        }
        out = (j >= 0) ? (float)(j + 1) : (float)t;
    }
    table[c * NB + t] = out;
}

__global__ void k_loss(const float* __restrict__ inp, const float* __restrict__ ref,
                       const float* __restrict__ msrc, const uint32_t* __restrict__ bits,
                       const float* __restrict__ table, double* __restrict__ accum) {
    int stride = gridDim.x * blockDim.x;
    float part = 0.0f;
    for (int p = blockIdx.x * blockDim.x + threadIdx.x; p < HH; p += stride) {
        float m = msrc[p];
        uint32_t f = (bits[p >> 5] >> (p & 31)) & 1u;
#pragma unroll
        for (int c = 0; c < 3; ++c) {
            float im = de_norm255(inp[c * HH + p]) * m;
            float rv = de_norm255(ref[c * HH + p]) * m;
            float match;
            if (f) {
                int b = (int)fminf(fmaxf(rv, 0.0f), 255.0f);  // clip then trunc, like jnp
                match = table[c * NB + b];
            } else {
                match = rv;
            }
            part += fabsf(im - match);
        }
    }
    // wave reduce (64 lanes)
#pragma unroll
    for (int off = 32; off > 0; off >>= 1) part += __shfl_down(part, off);
    __shared__ float wsum[4];
    int lane = threadIdx.x & 63;
    int wid = threadIdx.x >> 6;
    if (lane == 0) wsum[wid] = part;
    __syncthreads();
    if (threadIdx.x == 0) {
        float s = wsum[0] + wsum[1] + wsum[2] + wsum[3];
        atomicAdd(accum, (double)s);
    }
}

__global__ void k_final(const double* __restrict__ accum, float* __restrict__ out) {
    if (threadIdx.x == 0 && blockIdx.x == 0)
        out[0] = (float)(*accum / (double)(3.0 * (double)HH));
}

extern "C" void kernel_launch(void* const* d_in, const int* in_sizes, int n_in,
                              void* d_out, int out_size, void* d_ws, size_t ws_size,
                              hipStream_t stream) {
    const float* input  = (const float*)d_in[0];
    const float* target = (const float*)d_in[1];
    const float* ref    = (const float*)d_in[2];
    const float* msrc   = (const float*)d_in[3];
    const float* mtar   = (const float*)d_in[4];
    const int* i0 = (const int*)d_in[5];
    const int* i1 = (const int*)d_in[6];
    const int* i2 = (const int*)d_in[7];
    const int* i3 = (const int*)d_in[8];
    int nidx = in_sizes[5];

    char* ws = (char*)d_ws;
    double*   accum = (double*)(ws);
    uint32_t* hist  = (uint32_t*)(ws + 64);
    float*    table = (float*)(ws + 8192);
    uint32_t* bits  = (uint32_t*)(ws + 16384);

    k_init<<<512, 256, 0, stream>>>(hist, accum, bits);
    k_hist<<<2048, 256, 0, stream>>>(target, ref, msrc, mtar, i0, i1, i2, i3,
                                     hist, bits, nidx);
    k_table<<<3, 256, 0, stream>>>(hist, table);
    k_loss<<<2048, 256, 0, stream>>>(input, ref, msrc, bits, table, accum);
    k_final<<<1, 64, 0, stream>>>(accum, (float*)d_out);
}

// Round 2
// 248.796 us; speedup vs baseline: 1.5667x; 1.5667x over previous
//
#include <hip/hip_runtime.h>
#include <math.h>
#include <stdint.h>

#define H 2048
#define HH (H * H)
#define NB 256

// ws layout:
//   [0]        double accum                    (8 B)
//   [64]       uint32 hist[6][256]             (6144 B)  dst c0..2, then ref c0..2
//   [8192]     float  table[3][256]            (3072 B)
//   [16384]    uint32 bits[HH/32]              (512 KiB) scatter membership bitmask
//   [540672]   uint32 pdst[HH]                 (16 MiB)  packed bins of ref*msrc
//   [17317888] uint32 pref[HH]                 (16 MiB)  packed bins of tgt*mtar
#define OFF_HIST  64
#define OFF_TABLE 8192
#define OFF_BITS  16384
#define OFF_PDST  540672
#define OFF_PREF  17317888
#define WS_NEEDED (OFF_PREF + (size_t)4 * HH)

__global__ void k_init(uint32_t* __restrict__ hist, double* __restrict__ accum,
                       uint32_t* __restrict__ bits) {
    int tid = blockIdx.x * blockDim.x + threadIdx.x;
    if (tid == 0) *accum = 0.0;
    if (tid < 6 * NB) hist[tid] = 0u;
    int nw = HH / 32;
    for (int i = tid; i < nw; i += gridDim.x * blockDim.x) bits[i] = 0u;
}

__device__ __forceinline__ float de_norm255(float x) {
    return fminf(fmaxf((x + 1.0f) * 0.5f, 0.0f), 1.0f) * 255.0f;
}

__device__ __forceinline__ uint32_t bin_of(float v, float m) {
    // v*m in [0,255]; floor==trunc; clip redundant but cheap
    return (uint32_t)(de_norm255(v) * m);
}

#define E4(v, e) ((e) == 0 ? (v).x : (e) == 1 ? (v).y : (e) == 2 ? (v).z : (v).w)

// One thread per 4 pixels; packs both image sets.
__global__ void k_pack(const float* __restrict__ ref, const float* __restrict__ msrc,
                       const float* __restrict__ tgt, const float* __restrict__ mtar,
                       uint32_t* __restrict__ pdst, uint32_t* __restrict__ pref) {
    int q = blockIdx.x * blockDim.x + threadIdx.x;
    if (q >= HH / 4) return;
    float4 ms = ((const float4*)msrc)[q];
    float4 d0 = ((const float4*)(ref))[q];
    float4 d1 = ((const float4*)(ref + HH))[q];
    float4 d2 = ((const float4*)(ref + 2 * HH))[q];
    float4 mt = ((const float4*)mtar)[q];
    float4 r0 = ((const float4*)(tgt))[q];
    float4 r1 = ((const float4*)(tgt + HH))[q];
    float4 r2 = ((const float4*)(tgt + 2 * HH))[q];
    uint4 od, orf;
    uint32_t* pod = (uint32_t*)&od;
    uint32_t* por = (uint32_t*)&orf;
#pragma unroll
    for (int e = 0; e < 4; ++e) {
        float msE = E4(ms, e), mtE = E4(mt, e);
        pod[e] = bin_of(E4(d0, e), msE) | (bin_of(E4(d1, e), msE) << 8) |
                 (bin_of(E4(d2, e), msE) << 16);
        por[e] = bin_of(E4(r0, e), mtE) | (bin_of(E4(r1, e), mtE) << 8) |
                 (bin_of(E4(r2, e), mtE) << 16);
    }
    ((uint4*)pdst)[q] = od;
    ((uint4*)pref)[q] = orf;
}

// One thread per 4 samples; gathers 2 packed words per sample.
__global__ void k_gather(const int* __restrict__ i0, const int* __restrict__ i1,
                         const int* __restrict__ i2, const int* __restrict__ i3,
                         const uint32_t* __restrict__ pdst, const uint32_t* __restrict__ pref,
                         uint32_t* __restrict__ hist, uint32_t* __restrict__ bits,
                         int nquads) {
    __shared__ uint32_t lh[6 * NB];
    for (int i = threadIdx.x; i < 6 * NB; i += blockDim.x) lh[i] = 0u;
    __syncthreads();
    int q = blockIdx.x * blockDim.x + threadIdx.x;
    uint32_t zd = 0, zr = 0;
    if (q < nquads) {
        int4 a = ((const int4*)i0)[q];
        int4 b = ((const int4*)i1)[q];
        int4 c = ((const int4*)i2)[q];
        int4 d = ((const int4*)i3)[q];
        int pa[4] = {a.x * H + b.x, a.y * H + b.y, a.z * H + b.z, a.w * H + b.w};
        int pb[4] = {c.x * H + d.x, c.y * H + d.y, c.z * H + d.z, c.w * H + d.w};
        uint32_t vd[4], vr[4];
#pragma unroll
        for (int j = 0; j < 4; ++j) {
            vd[j] = pdst[pa[j]];
            vr[j] = pref[pb[j]];
        }
#pragma unroll
        for (int j = 0; j < 4; ++j) atomicOr(&bits[pa[j] >> 5], 1u << (pa[j] & 31));
#pragma unroll
        for (int j = 0; j < 4; ++j) {
            uint32_t v = vd[j];
            if (v == 0) {
                zd++;
            } else {
                atomicAdd(&lh[v & 255], 1u);
                atomicAdd(&lh[256 + ((v >> 8) & 255)], 1u);
                atomicAdd(&lh[512 + ((v >> 16) & 255)], 1u);
            }
            v = vr[j];
            if (v == 0) {
                zr++;
            } else {
                atomicAdd(&lh[768 + (v & 255)], 1u);
                atomicAdd(&lh[1024 + ((v >> 8) & 255)], 1u);
                atomicAdd(&lh[1280 + ((v >> 16) & 255)], 1u);
            }
        }
    }
    if (zd) {
        atomicAdd(&lh[0], zd);
        atomicAdd(&lh[256], zd);
        atomicAdd(&lh[512], zd);
    }
    if (zr) {
        atomicAdd(&lh[768], zr);
        atomicAdd(&lh[1024], zr);
        atomicAdd(&lh[1280], zr);
    }
    __syncthreads();
    for (int i = threadIdx.x; i < 6 * NB; i += blockDim.x)
        if (lh[i]) atomicAdd(&hist[i], lh[i]);
}

// Fallback (ws too small): original monolithic gather.
__global__ void k_hist_fb(const float* __restrict__ tgt, const float* __restrict__ ref,
                          const float* __restrict__ msrc, const float* __restrict__ mtar,
                          const int* __restrict__ i0, const int* __restrict__ i1,
                          const int* __restrict__ i2, const int* __restrict__ i3,
                          uint32_t* __restrict__ hist, uint32_t* __restrict__ bits,
                          int nidx) {
    __shared__ uint32_t lh[6 * NB];
    for (int i = threadIdx.x; i < 6 * NB; i += blockDim.x) lh[i] = 0u;
    __syncthreads();
    int stride = gridDim.x * blockDim.x;
    for (int k = blockIdx.x * blockDim.x + threadIdx.x; k < nidx; k += stride) {
        int pa = i0[k] * H + i1[k];
        int pb = i2[k] * H + i3[k];
        float ms = msrc[pa];
        float mt = mtar[pb];
        atomicOr(&bits[pa >> 5], 1u << (pa & 31));
#pragma unroll
        for (int c = 0; c < 3; ++c) {
            int bd = (int)(de_norm255(ref[c * HH + pa]) * ms);
            atomicAdd(&lh[c * NB + min(max(bd, 0), NB - 1)], 1u);
            int br = (int)(de_norm255(tgt[c * HH + pb]) * mt);
            atomicAdd(&lh[(3 + c) * NB + min(max(br, 0), NB - 1)], 1u);
        }
    }
    __syncthreads();
    for (int i = threadIdx.x; i < 6 * NB; i += blockDim.x)
        if (lh[i]) atomicAdd(&hist[i], lh[i]);
}

// 3 blocks (one per channel) x 256 threads
__global__ void k_table(const uint32_t* __restrict__ hist, float* __restrict__ table) {
    int c = blockIdx.x;
    int t = threadIdx.x;
    __shared__ uint32_t cd[NB], cr[NB];
    __shared__ float r[NB], a[NB];
    cd[t] = hist[c * NB + t];
    cr[t] = hist[(3 + c) * NB + t];
    __syncthreads();
    if (t == 0) {
        uint32_t s = 0;
        for (int i = 0; i < NB; ++i) { s += cd[i]; cd[i] = s; }
        s = 0;
        for (int i = 0; i < NB; ++i) { s += cr[i]; cr[i] = s; }
    }
    __syncthreads();
    float totd = (float)cd[NB - 1];
    float totr = (float)cr[NB - 1];
    r[t] = (float)cd[t] / totd;
    a[t] = (float)cr[t] / totr;
    __syncthreads();
    float out;
    if (t == 0) {
        out = 0.0f;
    } else if (t == NB - 1) {
        out = (float)(NB - 1);
    } else {
        float ri = r[t];
        int j = -1;
        for (int jj = 0; jj < NB - 1; ++jj) {
            if (ri >= a[jj] && ri <= a[jj + 1]) { j = jj; break; }
        }
        out = (j >= 0) ? (float)(j + 1) : (float)t;
    }
    table[c * NB + t] = out;
}

__global__ void k_loss(const float* __restrict__ inp, const float* __restrict__ ref,
                       const float* __restrict__ msrc, const uint32_t* __restrict__ bits,
                       const float* __restrict__ table, double* __restrict__ accum) {
    int stride = gridDim.x * blockDim.x;
    float part = 0.0f;
    for (int p = blockIdx.x * blockDim.x + threadIdx.x; p < HH; p += stride) {
        float m = msrc[p];
        uint32_t f = (bits[p >> 5] >> (p & 31)) & 1u;
#pragma unroll
        for (int c = 0; c < 3; ++c) {
            float im = de_norm255(inp[c * HH + p]) * m;
            float rv = de_norm255(ref[c * HH + p]) * m;
            float match;
            if (f) {
                int b = (int)fminf(fmaxf(rv, 0.0f), 255.0f);
                match = table[c * NB + b];
            } else {
                match = rv;
            }
            part += fabsf(im - match);
        }
    }
#pragma unroll
    for (int off = 32; off > 0; off >>= 1) part += __shfl_down(part, off);
    __shared__ float wsum[4];
    int lane = threadIdx.x & 63;
    int wid = threadIdx.x >> 6;
    if (lane == 0) wsum[wid] = part;
    __syncthreads();
    if (threadIdx.x == 0) {
        float s = wsum[0] + wsum[1] + wsum[2] + wsum[3];
        atomicAdd(accum, (double)s);
    }
}

__global__ void k_final(const double* __restrict__ accum, float* __restrict__ out) {
    if (threadIdx.x == 0 && blockIdx.x == 0)
        out[0] = (float)(*accum / (double)(3.0 * (double)HH));
}

extern "C" void kernel_launch(void* const* d_in, const int* in_sizes, int n_in,
                              void* d_out, int out_size, void* d_ws, size_t ws_size,
                              hipStream_t stream) {
    const float* input  = (const float*)d_in[0];
    const float* target = (const float*)d_in[1];
    const float* ref    = (const float*)d_in[2];
    const float* msrc   = (const float*)d_in[3];
    const float* mtar   = (const float*)d_in[4];
    const int* i0 = (const int*)d_in[5];
    const int* i1 = (const int*)d_in[6];
    const int* i2 = (const int*)d_in[7];
    const int* i3 = (const int*)d_in[8];
    int nidx = in_sizes[5];

    char* ws = (char*)d_ws;
    double*   accum = (double*)(ws);
    uint32_t* hist  = (uint32_t*)(ws + OFF_HIST);
    float*    table = (float*)(ws + OFF_TABLE);
    uint32_t* bits  = (uint32_t*)(ws + OFF_BITS);

    k_init<<<512, 256, 0, stream>>>(hist, accum, bits);

    if (ws_size >= WS_NEEDED && (nidx & 3) == 0) {
        uint32_t* pdst = (uint32_t*)(ws + OFF_PDST);
        uint32_t* pref = (uint32_t*)(ws + OFF_PREF);
        k_pack<<<(HH / 4 + 255) / 256, 256, 0, stream>>>(ref, msrc, target, mtar,
                                                         pdst, pref);
        int nquads = nidx / 4;
        k_gather<<<(nquads + 255) / 256, 256, 0, stream>>>(i0, i1, i2, i3, pdst, pref,
                                                           hist, bits, nquads);
    } else {
        k_hist_fb<<<2048, 256, 0, stream>>>(target, ref, msrc, mtar, i0, i1, i2, i3,
                                            hist, bits, nidx);
    }

    k_table<<<3, 256, 0, stream>>>(hist, table);
    k_loss<<<2048, 256, 0, stream>>>(input, ref, msrc, bits, table, accum);
    k_final<<<1, 64, 0, stream>>>(accum, (float*)d_out);
}